// Round 7
// baseline (429.143 us; speedup 1.0000x reference)
//
#include <hip/hip_runtime.h>
#include <stdint.h>

#define M_ROWS 65536
#define C_DIM  256
#define K_CLS  20
#define P_POS  2048
#define MARGIN_F 0.3f
#define EPS_D (0.0001f / 256.0f)
#define SCALE1 0x7F7F7F7Fu   /* e8m0 127 = 2^0 in all four bytes */
#define SCALE2 0x80808080u   /* e8m0 128 = 2^1 in all four bytes (A operand) */
#define GRID_N 640u          /* persistent grid; 3 blk/CU capacity = 768 >= 640 */

typedef float floatx4 __attribute__((ext_vector_type(4)));
typedef int   intx8   __attribute__((ext_vector_type(8)));
union Frag8 { intx8 v; uint4 q[2]; };

// async 16B/lane global -> LDS (wave-uniform LDS base + lane*16)
__device__ __forceinline__ void async_copy16(const void* g, void* l) {
    __builtin_amdgcn_global_load_lds(
        (const __attribute__((address_space(1))) void*)g,
        (__attribute__((address_space(3))) void*)l, 16, 0, 0);
}
__device__ __forceinline__ float sigm(float x) { return 1.f / (1.f + __expf(-x)); }

// flip fp8 e4m3 signs (sign-magnitude; sigmoid outputs have no NaN/Inf)
__device__ __forceinline__ void negA(Frag8& f) {
#pragma unroll
    for (int t = 0; t < 8; ++t) f.v[t] ^= (int)0x80808080u;
}

#define VMCNT2() asm volatile("s_waitcnt vmcnt(2)" ::: "memory")
#define VMCNT0() asm volatile("s_waitcnt vmcnt(0)" ::: "memory")

// one-shot grid barrier (counters zeroed by hipMemsetAsync before launch).
// Capacity-guaranteed co-residency: launch_bounds(256,3) + 26.8KB LDS ->
// 3 blocks/CU -> 768 slots >= 640 blocks, all dispatched at launch.
// __threadfence() = agent-scope fence: on gfx950 emits L2 writeback/inv,
// handling cross-XCD non-coherence (G16) for S8/xx/hp/hn handoffs.
__device__ __forceinline__ void gsync(unsigned int* c) {
    __syncthreads();
    if (threadIdx.x == 0) {
        __threadfence();   // release: flush my writes past non-coherent L2
        __hip_atomic_fetch_add(c, 1u, __ATOMIC_RELEASE, __HIP_MEMORY_SCOPE_AGENT);
        while (__hip_atomic_load(c, __ATOMIC_ACQUIRE,
                                 __HIP_MEMORY_SCOPE_AGENT) < GRID_N) {
            __builtin_amdgcn_s_sleep(2);
        }
        __threadfence();   // acquire: invalidate stale cached lines
    }
    __syncthreads();
}

// ------- loss helper: 16 fp8 channel diffs accumulated into dp/dn ----------
#define ACC16(UA, UP, UN)                                                     \
    {                                                                         \
        float xa, d;                                                          \
        xa = __builtin_amdgcn_cvt_f32_fp8((int)(UA), 0);                      \
        d = xa - __builtin_amdgcn_cvt_f32_fp8((int)(UP), 0); dp += d * d;     \
        d = xa - __builtin_amdgcn_cvt_f32_fp8((int)(UN), 0); dn += d * d;     \
        xa = __builtin_amdgcn_cvt_f32_fp8((int)(UA), 1);                      \
        d = xa - __builtin_amdgcn_cvt_f32_fp8((int)(UP), 1); dp += d * d;     \
        d = xa - __builtin_amdgcn_cvt_f32_fp8((int)(UN), 1); dn += d * d;     \
        xa = __builtin_amdgcn_cvt_f32_fp8((int)(UA), 2);                      \
        d = xa - __builtin_amdgcn_cvt_f32_fp8((int)(UP), 2); dp += d * d;     \
        d = xa - __builtin_amdgcn_cvt_f32_fp8((int)(UN), 2); dn += d * d;     \
        xa = __builtin_amdgcn_cvt_f32_fp8((int)(UA), 3);                      \
        d = xa - __builtin_amdgcn_cvt_f32_fp8((int)(UP), 3); dp += d * d;     \
        d = xa - __builtin_amdgcn_cvt_f32_fp8((int)(UN), 3); dn += d * d;     \
    }

// =================== R22: fully fused persistent kernel =====================
// Rationale: select_k is within ~20% of its structure-class ceiling (29% of
// MX peak vs m148's 35% at 16x deeper K; 3 sync structures / 2 tile sizes /
// 2 occupancies / 2 LDS styles all 62-74 us). The non-select constant
// (~95-106 us across ALL rounds) >> bottom-up kernel estimates (~25 us) ->
// ~70 us of inter-dispatch gaps. Fuse everything into one persistent kernel:
//   P1 sigmoid+fp8-pack+norms (grid-stride) -> gsync
//   P2 two select jobs/block (job, job+640: same (k,type) -> L2 reuse) -> gsync
//   P3 loss, 4 chunks/block -> per-block partial -> arrive
//   P4 block 0 reduces 640 partials -> out
// Select body = R21's verbatim (typed-LDS Bt4, MFMA-folded yy-2xy, 3-ring
// counted vmcnt, monotone-key atomics; NEVER funnel same-address atomics).
__global__ __launch_bounds__(256, 3) void fused_k(
        const float* __restrict__ feat,
        unsigned int* __restrict__ S8,
        float* __restrict__ xx,
        const int* __restrict__ pos_idx,
        const int* __restrict__ neg_idx,
        unsigned int* __restrict__ hp,
        unsigned int* __restrict__ hn,
        float* __restrict__ partials,
        unsigned int* __restrict__ bars,
        float* __restrict__ out) {
    __shared__ __align__(16) uint4 Bt4[3][512];   // 24 KiB ring
    __shared__ float yyL[512];                    // 2 KiB
    __shared__ float sm[16];

    const int tid    = threadIdx.x;
    const int wave   = tid >> 6;
    const int lane   = tid & 63;
    const int lane15 = lane & 15;
    const int quad   = lane >> 4;
    const char* S8B  = (const char*)S8;           // row stride 256 B

    // ---------------- P1: sigmoid -> fp8 table + row norms ------------------
    for (int g = blockIdx.x; g < M_ROWS / 4; g += (int)GRID_N) {
        const int row = g * 4 + wave;
        const float4 v = *(const float4*)(feat + (size_t)row * C_DIM + lane * 4);
        const int p01 = __builtin_amdgcn_cvt_pk_fp8_f32(sigm(v.x), sigm(v.y), 0, false);
        const int p23 = __builtin_amdgcn_cvt_pk_fp8_f32(sigm(v.z), sigm(v.w), 0, false);
        S8[(size_t)row * 64 + lane] =
            (unsigned int)(p01 & 0xFFFF) | ((unsigned int)p23 << 16);
        const float q0 = __builtin_amdgcn_cvt_f32_fp8(p01, 0);
        const float q1 = __builtin_amdgcn_cvt_f32_fp8(p01, 1);
        const float q2 = __builtin_amdgcn_cvt_f32_fp8(p23, 0);
        const float q3 = __builtin_amdgcn_cvt_f32_fp8(p23, 1);
        float sum = q0 * q0 + q1 * q1 + q2 * q2 + q3 * q3;
#pragma unroll
        for (int off = 32; off; off >>= 1) sum += __shfl_down(sum, off);
        if (lane == 0) xx[row] = sum;
    }
    {   // hp/hn merge-key init (640*256 = 163840 >= 40960: single pass)
        const int idx = blockIdx.x * 256 + tid;
        if (idx < K_CLS * P_POS) { hp[idx] = 0u; hn[idx] = 0xFFFFFFFFu; }
    }
    gsync(&bars[0]);

    // ---------------- P2: two select jobs per block -------------------------
    for (int jj = 0; jj < 2; ++jj) {
        const int job = (int)blockIdx.x + jj * (int)GRID_N;   // 0..1279
        __syncthreads();   // prior job's Bt/yyL readers done; drains vmcnt(0)

        const int ctid  = job % 40;
        const int rest  = job / 40;        // 0..31
        const int i_blk = rest >> 2;       // 0..7
        const int jq    = rest & 3;        // 0..3
        const int k     = ctid >> 1;
        const int isNeg = ctid & 1;
        const int i0    = i_blk * 256;
        const int j0    = jq * 512;

        const int* __restrict__ idxA = pos_idx + k * P_POS;
        const int* __restrict__ idxB = (isNeg ? neg_idx : pos_idx) + k * P_POS;
        unsigned int* outKey         = (isNeg ? hn : hp) + k * P_POS;

        // staging geometry: 8 ops/tile (2 per wave), 4 rows per op
        const int rl  = lane >> 4;
        const int cch = lane & 15;
        int rloc[2], soff[2];
#pragma unroll
        for (int c = 0; c < 2; ++c) {
            rloc[c] = (wave * 2 + c) * 4 + rl;
            soff[c] = (cch ^ (rloc[c] & 15)) << 4;
        }

        // preload ALL staging row indices (rows < 65536 -> 2x16-bit pack)
        uint32_t g_pk[16];
#pragma unroll
        for (int t = 0; t < 16; ++t) {
            const uint32_t a0 = (uint32_t)idxB[j0 + t * 32 + rloc[0]];
            const uint32_t a1 = (uint32_t)idxB[j0 + t * 32 + rloc[1]];
            g_pk[t] = (a0 & 0xFFFFu) | (a1 << 16);
        }
        // yy table for this j-quarter
#pragma unroll
        for (int t = 0; t < 2; ++t) {
            const int jjx = t * 256 + tid;
            yyL[jjx] = xx[idxB[j0 + jjx]];
        }
        // A fragments, sign-flipped (with A-scale 2^1 -> MFMA gives -2*x.y)
        Frag8 A_reg[4][2];
#pragma unroll
        for (int si = 0; si < 4; ++si) {
            const int gi = idxA[i0 + wave * 64 + si * 16 + lane15];
            const char* rb = S8B + ((size_t)(uint32_t)gi << 8) + quad * 32;
#pragma unroll
            for (int s = 0; s < 2; ++s) {
                A_reg[si][s].q[0] = *(const uint4*)(rb + s * 128);
                A_reg[si][s].q[1] = *(const uint4*)(rb + s * 128 + 16);
                negA(A_reg[si][s]);
            }
        }
        const int bidx0 = lane15 * 16 + ((quad * 2) ^ lane15);

        float bestv[16];
        const float binit = isNeg ? 3.4e38f : -3.4e38f;
#pragma unroll
        for (int t = 0; t < 16; ++t) bestv[t] = binit;

        // prologue: issue tiles 0 and 1
#pragma unroll
        for (int t = 0; t < 2; ++t) {
            char* lb = (char*)Bt4[t] + (wave * 2) * 1024;
            async_copy16(S8B + ((size_t)(g_pk[t] & 0xFFFFu) << 8) + soff[0], lb);
            async_copy16(S8B + ((size_t)(g_pk[t] >> 16) << 8) + soff[1], lb + 1024);
        }
        __syncthreads();   // full drain: tiles 0,1 landed; yyL visible

#pragma unroll
        for (int jc = 0; jc < 16; ++jc) {
            if (jc) {
                if (jc == 15) VMCNT0(); else VMCNT2();
                __builtin_amdgcn_s_barrier();
                __builtin_amdgcn_sched_barrier(0);
            }
            const float yv0 = yyL[(jc << 5) + lane15];
            const float yv1 = yyL[(jc << 5) + 16 + lane15];

            if (jc < 14) {
                const uint32_t pk = g_pk[jc + 2];
                char* lb = (char*)Bt4[(jc + 2) % 3] + (wave * 2) * 1024;
                async_copy16(S8B + ((size_t)(pk & 0xFFFFu) << 8) + soff[0], lb);
                async_copy16(S8B + ((size_t)(pk >> 16) << 8) + soff[1], lb + 1024);
            }

            const floatx4 yv4_0 = {yv0, yv0, yv0, yv0};
            const floatx4 yv4_1 = {yv1, yv1, yv1, yv1};
            floatx4 acc[2][4];
            {
                Frag8 bf0, bf1;
                bf0.q[0] = Bt4[jc % 3][bidx0];
                bf0.q[1] = Bt4[jc % 3][bidx0 ^ 1];
                bf1.q[0] = Bt4[jc % 3][bidx0 + 256];
                bf1.q[1] = Bt4[jc % 3][(bidx0 ^ 1) + 256];
#pragma unroll
                for (int si = 0; si < 4; ++si)
                    acc[0][si] = __builtin_amdgcn_mfma_scale_f32_16x16x128_f8f6f4(
                        A_reg[si][0].v, bf0.v, yv4_0, 0, 0, 0, SCALE2, 0, SCALE1);
#pragma unroll
                for (int si = 0; si < 4; ++si)
                    acc[1][si] = __builtin_amdgcn_mfma_scale_f32_16x16x128_f8f6f4(
                        A_reg[si][0].v, bf1.v, yv4_1, 0, 0, 0, SCALE2, 0, SCALE1);
            }
            {
                Frag8 bf0, bf1;
                bf0.q[0] = Bt4[jc % 3][bidx0 ^ 8];
                bf0.q[1] = Bt4[jc % 3][bidx0 ^ 9];
                bf1.q[0] = Bt4[jc % 3][(bidx0 ^ 8) + 256];
                bf1.q[1] = Bt4[jc % 3][(bidx0 ^ 9) + 256];
#pragma unroll
                for (int si = 0; si < 4; ++si)
                    acc[0][si] = __builtin_amdgcn_mfma_scale_f32_16x16x128_f8f6f4(
                        A_reg[si][1].v, bf0.v, acc[0][si], 0, 0, 0, SCALE2, 0, SCALE1);
#pragma unroll
                for (int si = 0; si < 4; ++si)
                    acc[1][si] = __builtin_amdgcn_mfma_scale_f32_16x16x128_f8f6f4(
                        A_reg[si][1].v, bf1.v, acc[1][si], 0, 0, 0, SCALE2, 0, SCALE1);
            }

            const uint32_t jb0 = (uint32_t)((j0 + (jc << 5)) | lane15);
            const uint32_t jb1 = jb0 | 16u;
#pragma unroll
            for (int si = 0; si < 4; ++si)
#pragma unroll
                for (int r = 0; r < 4; ++r) {
                    const float e0 = __uint_as_float(
                        (__float_as_uint(acc[0][si][r]) & 0xFFFFF800u) | jb0);
                    const float e1 = __uint_as_float(
                        (__float_as_uint(acc[1][si][r]) & 0xFFFFF800u) | jb1);
                    const int slot = si * 4 + r;
                    bestv[slot] = isNeg ? fminf(fminf(bestv[slot], e0), e1)
                                        : fmaxf(fmaxf(bestv[slot], e0), e1);
                }
        }

        // reduce over the 16 column-lanes; merge via monotone-key atomics
#pragma unroll
        for (int slot = 0; slot < 16; ++slot) {
#pragma unroll
            for (int off = 1; off < 16; off <<= 1) {
                const float ov = __shfl_xor(bestv[slot], off);
                bestv[slot] = isNeg ? fminf(bestv[slot], ov) : fmaxf(bestv[slot], ov);
            }
        }
        if (lane15 == 0) {
#pragma unroll
            for (int si = 0; si < 4; ++si)
#pragma unroll
                for (int r = 0; r < 4; ++r) {
                    const int row = wave * 64 + si * 16 + quad * 4 + r;
                    const uint32_t u = __float_as_uint(bestv[si * 4 + r]);
                    const uint32_t key = (u & 0x80000000u) ? ~u : (u | 0x80000000u);
                    if (isNeg) atomicMin(&outKey[i0 + row], key);
                    else       atomicMax(&outKey[i0 + row], key);
                }
        }
    }
    gsync(&bars[1]);

    // ---------------- P3: loss, 4 chunks of 16 anchors ----------------------
    const int grp = tid >> 4;     // 0..15
    float lsum = 0.f;
    for (int c = 0; c < 4; ++c) {
        const int a = ((int)blockIdx.x * 4 + c) * 16 + grp;   // 0..40959
        const int k = a >> 11;
        const int i = a & 2047;
        const int* pidx = pos_idx + (k << 11);
        const int* nidx = neg_idx + (k << 11);
        const unsigned int kp = hp[a], kn = hn[a];
        const int jp = (int)((kp & 0x80000000u) ? (kp & 2047u) : ((~kp) & 2047u));
        const int jn = (int)((kn & 0x80000000u) ? (kn & 2047u) : ((~kn) & 2047u));
        const int ga = pidx[i];
        const int gp = pidx[jp];
        const int gn = nidx[jn];
        const uint4 va = *(const uint4*)(S8B + ((size_t)(uint32_t)ga << 8) + lane15 * 16);
        const uint4 vp = *(const uint4*)(S8B + ((size_t)(uint32_t)gp << 8) + lane15 * 16);
        const uint4 vn = *(const uint4*)(S8B + ((size_t)(uint32_t)gn << 8) + lane15 * 16);
        float dp = 0.f, dn = 0.f;
        ACC16(va.x, vp.x, vn.x)
        ACC16(va.y, vp.y, vn.y)
        ACC16(va.z, vp.z, vn.z)
        ACC16(va.w, vp.w, vn.w)
#pragma unroll
        for (int off = 1; off < 16; off <<= 1) {
            dp += __shfl_xor(dp, off);
            dn += __shfl_xor(dn, off);
        }
        if (lane15 == 0) {
            const float d_p = sqrtf(fmaxf(dp, 0.f) + EPS_D);
            const float d_n = sqrtf(fmaxf(dn, 0.f) + EPS_D);
            lsum += fmaxf(MARGIN_F + d_p - d_n, 0.f);
        }
    }
    __syncthreads();
    if ((tid & 15) == 0) sm[grp] = lsum;
    __syncthreads();
    if (tid == 0) {
        float s = 0.f;
#pragma unroll
        for (int g = 0; g < 16; ++g) s += sm[g];
        partials[blockIdx.x] = s;
        __threadfence();
        __hip_atomic_fetch_add(&bars[2], 1u, __ATOMIC_RELEASE,
                               __HIP_MEMORY_SCOPE_AGENT);
    }

    // ---------------- P4: block 0 reduces the 640 partials ------------------
    if (blockIdx.x == 0) {
        if (tid == 0) {
            while (__hip_atomic_load(&bars[2], __ATOMIC_ACQUIRE,
                                     __HIP_MEMORY_SCOPE_AGENT) < GRID_N) {
                __builtin_amdgcn_s_sleep(2);
            }
            __threadfence();
        }
        __syncthreads();
        float s = 0.f;
        for (int i = tid; i < (int)GRID_N; i += 256) s += partials[i];
#pragma unroll
        for (int off = 32; off; off >>= 1) s += __shfl_down(s, off);
        __syncthreads();
        if (lane == 0) sm[wave] = s;
        __syncthreads();
        if (tid == 0)
            out[0] = (sm[0] + sm[1] + sm[2] + sm[3]) * (1.0f / (float)P_POS);
    }
}

extern "C" void kernel_launch(void* const* d_in, const int* in_sizes, int n_in,
                              void* d_out, int out_size, void* d_ws, size_t ws_size,
                              hipStream_t stream) {
    const float* feat    = (const float*)d_in[0];
    const int*   pos_idx = (const int*)d_in[1];
    const int*   neg_idx = (const int*)d_in[2];

    char* ws = (char*)d_ws;
    unsigned int* S8 = (unsigned int*)ws;                     // 16 MiB fp8 table
    float*        xx = (float*)(ws + 16777216);               // 256 KiB norms
    unsigned int* hp = (unsigned int*)(ws + 17039360);        // 160 KiB keys
    unsigned int* hn = (unsigned int*)(ws + 17203200);        // 160 KiB keys
    float*  partials = (float*)(ws + 17367040);               // 2.5 KiB
    unsigned int* bars = (unsigned int*)(ws + 17369600);      // 3 barrier ctrs

    hipMemsetAsync(bars, 0, 16, stream);   // zero one-shot barrier counters
    fused_k<<<GRID_N, 256, 0, stream>>>(feat, S8, xx, pos_idx, neg_idx,
                                        hp, hn, partials, bars, (float*)d_out);
}

// Round 8
// 166.077 us; speedup vs baseline: 2.5840x; 2.5840x over previous
//
#include <hip/hip_runtime.h>
#include <stdint.h>

#define M_ROWS 65536
#define C_DIM  256
#define K_CLS  20
#define P_POS  2048
#define MARGIN_F 0.3f
#define EPS_D (0.0001f / 256.0f)
#define SCALE1 0x7F7F7F7Fu   /* e8m0 127 = 2^0 in all four bytes */
#define SCALE2 0x80808080u   /* e8m0 128 = 2^1 in all four bytes (A operand) */

typedef float floatx4 __attribute__((ext_vector_type(4)));
typedef int   intx8   __attribute__((ext_vector_type(8)));
union Frag8 { intx8 v; uint4 q[2]; };

// async 16B/lane global -> LDS (wave-uniform LDS base + lane*16)
__device__ __forceinline__ void async_copy16(const void* g, void* l) {
    __builtin_amdgcn_global_load_lds(
        (const __attribute__((address_space(1))) void*)g,
        (__attribute__((address_space(3))) void*)l, 16, 0, 0);
}
__device__ __forceinline__ float sigm(float x) { return 1.f / (1.f + __expf(-x)); }

// flip fp8 e4m3 signs (sign-magnitude; sigmoid outputs have no NaN/Inf)
__device__ __forceinline__ void negA(Frag8& f) {
#pragma unroll
    for (int t = 0; t < 8; ++t) f.v[t] ^= (int)0x80808080u;
}

#define VMCNT2() asm volatile("s_waitcnt vmcnt(2)" ::: "memory")
#define VMCNT0() asm volatile("s_waitcnt vmcnt(0)" ::: "memory")

// ------- Kernel 1: sigmoid -> fp8 e4m3 table + fp8-exact row norms ----------
// R23: 2048 blocks, grid-stride x8 (was 16384 blocks doing ONE float4/thread
// each -> ~20-40 us of pure block-dispatch overhead vs a ~13 us BW floor).
// R22's persistent-fusion attempt showed grid barriers cost far more than
// launch gaps (agent-scope acquire spin = per-poll cache invalidates).
__global__ __launch_bounds__(256) void sigmoid_norm_k(
        const float* __restrict__ feat,
        unsigned int* __restrict__ S8,     // [M][64] uint = 256 fp8/row
        float* __restrict__ xx,
        unsigned int* __restrict__ hp,
        unsigned int* __restrict__ hn,
        float* __restrict__ out) {
    {
        const int idx = blockIdx.x * 256 + threadIdx.x;
        if (idx < K_CLS * P_POS) { hp[idx] = 0u; hn[idx] = 0xFFFFFFFFu; }
        if (idx == 0) out[0] = 0.f;   // loss accumulator (reduce_k atomicAdds)
    }
    const int wave = threadIdx.x >> 6, lane = threadIdx.x & 63;
    for (int g = blockIdx.x; g < M_ROWS / 4; g += 2048) {
        const int row = g * 4 + wave;
        const float4 v = *(const float4*)(feat + (size_t)row * C_DIM + lane * 4);

        const int p01 = __builtin_amdgcn_cvt_pk_fp8_f32(sigm(v.x), sigm(v.y), 0, false);
        const int p23 = __builtin_amdgcn_cvt_pk_fp8_f32(sigm(v.z), sigm(v.w), 0, false);
        S8[(size_t)row * 64 + lane] =
            (unsigned int)(p01 & 0xFFFF) | ((unsigned int)p23 << 16);

        const float q0 = __builtin_amdgcn_cvt_f32_fp8(p01, 0);
        const float q1 = __builtin_amdgcn_cvt_f32_fp8(p01, 1);
        const float q2 = __builtin_amdgcn_cvt_f32_fp8(p23, 0);
        const float q3 = __builtin_amdgcn_cvt_f32_fp8(p23, 1);
        float sum = q0 * q0 + q1 * q1 + q2 * q2 + q3 * q3;
#pragma unroll
        for (int off = 32; off; off >>= 1) sum += __shfl_down(sum, off);
        if (lane == 0) xx[row] = sum;
    }
}

// ---------- Kernel 2: fused MX-fp8 (K=128) distance-GEMM + arg-select -------
// R21 body VERBATIM (best measured: 62-64 us, ~29% of MX-fp8 peak; within
// ~20% of its structure-class ceiling per m148 at 16x deeper K). History:
// 3 sync structures / 2 tile sizes / 2 occupancy levels / 2 LDS addressing
// styles all land 62-74 us, MfmaUtil 22-26% -> structure-class bound, leave.
// Typed-LDS Bt4 (guaranteed ds_read_b128), 3-ring counted vmcnt, MFMA-folded
// yy-2xy (A sign-flip fp8 + A-scale 2^1 + C=yv splat), monotone-key atomics
// (2048-entry arrays; NEVER funnel same-address atomics: R18 cost +20 us;
// R19 lesson: never force occupancy via launch_bounds -> unified-file spills).
// Grid 1280 = 8 i_blk x 4 jq x 40 (k,type); bid%40 -> same XCD per (k,type).
__global__ __launch_bounds__(256, 3) void select_k(
        const unsigned int* __restrict__ S8,
        const float* __restrict__ xx,
        const int* __restrict__ pos_idx,
        const int* __restrict__ neg_idx,
        unsigned int* __restrict__ hp,
        unsigned int* __restrict__ hn) {
    __shared__ __align__(16) uint4 Bt4[3][512];   // 3 x 8 KiB ring
    __shared__ float yyL[512];                    // 2 KiB

    const int tid    = threadIdx.x;
    const int w      = tid >> 6;        // 0..3 (i-quarter)
    const int lane   = tid & 63;
    const int lane15 = lane & 15;
    const int quad   = lane >> 4;

    const int bid    = blockIdx.x;      // 1280 = 32 (i_blk,jq) x 40 (k,type)
    const int ctid   = bid % 40;
    const int rest   = bid / 40;        // 0..31
    const int i_blk  = rest >> 2;       // 0..7
    const int jq     = rest & 3;        // 0..3
    const int k      = ctid >> 1;
    const int isNeg  = ctid & 1;
    const int i0     = i_blk * 256;
    const int j0     = jq * 512;        // 16 tiles of 32 j

    const int* __restrict__ idxA = pos_idx + k * P_POS;
    const int* __restrict__ idxB = (isNeg ? neg_idx : pos_idx) + k * P_POS;
    unsigned int* outKey         = (isNeg ? hn : hp) + k * P_POS;

    const char* S8B = (const char*)S8;          // row stride 256 B

    // ---- staging geometry: 8 ops/tile (2 per wave), 4 rows per op ----
    const int rl  = lane >> 4;          // 0..3
    const int cch = lane & 15;
    int rloc[2], soff[2];
#pragma unroll
    for (int c = 0; c < 2; ++c) {
        rloc[c] = (w * 2 + c) * 4 + rl;                  // tile-local row
        soff[c] = (cch ^ (rloc[c] & 15)) << 4;           // swizzled source chunk
    }

    // ---- preload ALL staging row indices (rows < 65536 -> 2x16-bit pack) ---
    uint32_t g_pk[16];
#pragma unroll
    for (int t = 0; t < 16; ++t) {
        const uint32_t a0 = (uint32_t)idxB[j0 + t * 32 + rloc[0]];
        const uint32_t a1 = (uint32_t)idxB[j0 + t * 32 + rloc[1]];
        g_pk[t] = (a0 & 0xFFFFu) | (a1 << 16);
    }

    // ---- yy table for this j-quarter, once per block (2 gathers/thread) ----
#pragma unroll
    for (int t = 0; t < 2; ++t) {
        const int jj = t * 256 + tid;
        yyL[jj] = xx[idxB[j0 + jj]];
    }

    // ---- A fragments: row i0+w*64+si*16+lane15, k0 = quad*32 + s*128 ----
    // Sign-flipped so that (with A-scale = 2^1) MFMA accumulates -2*x.y.
    Frag8 A_reg[4][2];
#pragma unroll
    for (int si = 0; si < 4; ++si) {
        const int gi = idxA[i0 + w * 64 + si * 16 + lane15];
        const char* rb = S8B + ((size_t)(uint32_t)gi << 8) + quad * 32;
#pragma unroll
        for (int s = 0; s < 2; ++s) {
            A_reg[si][s].q[0] = *(const uint4*)(rb + s * 128);
            A_reg[si][s].q[1] = *(const uint4*)(rb + s * 128 + 16);
            negA(A_reg[si][s]);
        }
    }

    // ---- LDS read base (uint4 index): s=0 lo chunk c0=quad*2, row=lane15;
    //      hi = ^1, s=1 = ^8 (hi ^9), ct=1 = +256.
    const int bidx0 = lane15 * 16 + ((quad * 2) ^ lane15);

    float bestv[16];
    const float binit = isNeg ? 3.4e38f : -3.4e38f;
#pragma unroll
    for (int t = 0; t < 16; ++t) bestv[t] = binit;

    // ---- prologue: issue tiles 0 and 1 (4 copies/wave) ----
#pragma unroll
    for (int t = 0; t < 2; ++t) {
        char* lb = (char*)Bt4[t] + (w * 2) * 1024;
        async_copy16(S8B + ((size_t)(g_pk[t] & 0xFFFFu) << 8) + soff[0], lb);
        async_copy16(S8B + ((size_t)(g_pk[t] >> 16) << 8) + soff[1], lb + 1024);
    }

    __syncthreads();   // one-time full drain: tiles 0,1 in LDS; yyL visible

#pragma unroll
    for (int jc = 0; jc < 16; ++jc) {
        if (jc) {
            // my copies for tile jc landed (2 newer may stay in flight);
            // barrier => everyone's copies landed AND everyone finished
            // reading buf[(jc-1)%3] (the one tile jc+2 will overwrite).
            if (jc == 15) VMCNT0(); else VMCNT2();
            __builtin_amdgcn_s_barrier();
            __builtin_amdgcn_sched_barrier(0);
        }

        // yv: LDS broadcast (same address across the quad -> conflict-free)
        const float yv0 = yyL[(jc << 5) + lane15];
        const float yv1 = yyL[(jc << 5) + 16 + lane15];

        // prefetch tile jc+2 into buf[(jc+2)%3] (read last iter by all waves)
        if (jc < 14) {
            const uint32_t pk = g_pk[jc + 2];
            char* lb = (char*)Bt4[(jc + 2) % 3] + (w * 2) * 1024;
            async_copy16(S8B + ((size_t)(pk & 0xFFFFu) << 8) + soff[0], lb);
            async_copy16(S8B + ((size_t)(pk >> 16) << 8) + soff[1], lb + 1024);
        }

        // ---- compute: 2 K-steps of 128; explicit-LDS b128 reads feed 16
        //      MFMAs; first K-step carries yy in the C operand.
        const floatx4 yv4_0 = {yv0, yv0, yv0, yv0};
        const floatx4 yv4_1 = {yv1, yv1, yv1, yv1};
        floatx4 acc[2][4];
        {
            Frag8 bf0, bf1;
            bf0.q[0] = Bt4[jc % 3][bidx0];
            bf0.q[1] = Bt4[jc % 3][bidx0 ^ 1];
            bf1.q[0] = Bt4[jc % 3][bidx0 + 256];
            bf1.q[1] = Bt4[jc % 3][(bidx0 ^ 1) + 256];
#pragma unroll
            for (int si = 0; si < 4; ++si)
                acc[0][si] = __builtin_amdgcn_mfma_scale_f32_16x16x128_f8f6f4(
                    A_reg[si][0].v, bf0.v, yv4_0, 0, 0,
                    0, SCALE2, 0, SCALE1);
#pragma unroll
            for (int si = 0; si < 4; ++si)
                acc[1][si] = __builtin_amdgcn_mfma_scale_f32_16x16x128_f8f6f4(
                    A_reg[si][0].v, bf1.v, yv4_1, 0, 0,
                    0, SCALE2, 0, SCALE1);
        }
        {
            Frag8 bf0, bf1;
            bf0.q[0] = Bt4[jc % 3][bidx0 ^ 8];
            bf0.q[1] = Bt4[jc % 3][bidx0 ^ 9];
            bf1.q[0] = Bt4[jc % 3][(bidx0 ^ 8) + 256];
            bf1.q[1] = Bt4[jc % 3][(bidx0 ^ 9) + 256];
#pragma unroll
            for (int si = 0; si < 4; ++si)
                acc[0][si] = __builtin_amdgcn_mfma_scale_f32_16x16x128_f8f6f4(
                    A_reg[si][1].v, bf0.v, acc[0][si], 0, 0,
                    0, SCALE2, 0, SCALE1);
#pragma unroll
            for (int si = 0; si < 4; ++si)
                acc[1][si] = __builtin_amdgcn_mfma_scale_f32_16x16x128_f8f6f4(
                    A_reg[si][1].v, bf1.v, acc[1][si], 0, 0,
                    0, SCALE2, 0, SCALE1);
        }

        // ---- epilogue: acc already = yy-2xy. enc = (bits&~2047)|j ----
        const uint32_t jb0 = (uint32_t)((j0 + (jc << 5)) | lane15);
        const uint32_t jb1 = jb0 | 16u;
#pragma unroll
        for (int si = 0; si < 4; ++si)
#pragma unroll
            for (int r = 0; r < 4; ++r) {
                const float e0 = __uint_as_float(
                    (__float_as_uint(acc[0][si][r]) & 0xFFFFF800u) | jb0);
                const float e1 = __uint_as_float(
                    (__float_as_uint(acc[1][si][r]) & 0xFFFFF800u) | jb1);
                const int slot = si * 4 + r;
                bestv[slot] = isNeg ? fminf(fminf(bestv[slot], e0), e1)
                                    : fmaxf(fmaxf(bestv[slot], e0), e1);
            }
    }

    // ---- reduce over the 16 column-lanes (index rides in the bits) ----
#pragma unroll
    for (int slot = 0; slot < 16; ++slot) {
#pragma unroll
        for (int off = 1; off < 16; off <<= 1) {
            const float ov = __shfl_xor(bestv[slot], off);
            bestv[slot] = isNeg ? fminf(bestv[slot], ov) : fmaxf(bestv[slot], ov);
        }
    }
    // ---- merge across j-quarters: monotone-mapped key + device atomics ----
    if (lane15 == 0) {
#pragma unroll
        for (int si = 0; si < 4; ++si)
#pragma unroll
            for (int r = 0; r < 4; ++r) {
                const int row = w * 64 + si * 16 + quad * 4 + r;
                const uint32_t u = __float_as_uint(bestv[si * 4 + r]);
                const uint32_t key = (u & 0x80000000u) ? ~u : (u | 0x80000000u);
                if (isNeg) atomicMin(&outKey[i0 + row], key);
                else       atomicMax(&outKey[i0 + row], key);
            }
    }
}

// ------- Kernel 3: per-anchor pdist from fp8 table (16 lanes/anchor) --------
// R23: 640 blocks x 4 anchor-chunks (was 2560 blocks x 1 -> dispatch overhead).
#define ACC16(UA, UP, UN)                                                     \
    {                                                                         \
        float xa, d;                                                          \
        xa = __builtin_amdgcn_cvt_f32_fp8((int)(UA), 0);                      \
        d = xa - __builtin_amdgcn_cvt_f32_fp8((int)(UP), 0); dp += d * d;     \
        d = xa - __builtin_amdgcn_cvt_f32_fp8((int)(UN), 0); dn += d * d;     \
        xa = __builtin_amdgcn_cvt_f32_fp8((int)(UA), 1);                      \
        d = xa - __builtin_amdgcn_cvt_f32_fp8((int)(UP), 1); dp += d * d;     \
        d = xa - __builtin_amdgcn_cvt_f32_fp8((int)(UN), 1); dn += d * d;     \
        xa = __builtin_amdgcn_cvt_f32_fp8((int)(UA), 2);                      \
        d = xa - __builtin_amdgcn_cvt_f32_fp8((int)(UP), 2); dp += d * d;     \
        d = xa - __builtin_amdgcn_cvt_f32_fp8((int)(UN), 2); dn += d * d;     \
        xa = __builtin_amdgcn_cvt_f32_fp8((int)(UA), 3);                      \
        d = xa - __builtin_amdgcn_cvt_f32_fp8((int)(UP), 3); dp += d * d;     \
        d = xa - __builtin_amdgcn_cvt_f32_fp8((int)(UN), 3); dn += d * d;     \
    }

__global__ __launch_bounds__(256) void loss_k(
        const unsigned int* __restrict__ S8,
        const int* __restrict__ pos_idx,
        const int* __restrict__ neg_idx,
        const unsigned int* __restrict__ hp,
        const unsigned int* __restrict__ hn,
        float* __restrict__ terms) {
    const int tid    = threadIdx.x;
    const int lane15 = tid & 15;
    const int grp    = tid >> 4;               // 0..15: anchor group in block
    const char* S8B = (const char*)S8;
#pragma unroll
    for (int c = 0; c < 4; ++c) {
        const int a = ((int)blockIdx.x * 4 + c) * 16 + grp;   // 0..40959
        const int k = a >> 11;
        const int i = a & 2047;
        const int* pidx = pos_idx + (k << 11);
        const int* nidx = neg_idx + (k << 11);
        const unsigned int kp = hp[a], kn = hn[a];
        const int jp = (int)((kp & 0x80000000u) ? (kp & 2047u) : ((~kp) & 2047u));
        const int jn = (int)((kn & 0x80000000u) ? (kn & 2047u) : ((~kn) & 2047u));
        const int ga = pidx[i];
        const int gp = pidx[jp];
        const int gn = nidx[jn];

        const uint4 va = *(const uint4*)(S8B + ((size_t)(uint32_t)ga << 8) + lane15 * 16);
        const uint4 vp = *(const uint4*)(S8B + ((size_t)(uint32_t)gp << 8) + lane15 * 16);
        const uint4 vn = *(const uint4*)(S8B + ((size_t)(uint32_t)gn << 8) + lane15 * 16);

        float dp = 0.f, dn = 0.f;
        ACC16(va.x, vp.x, vn.x)
        ACC16(va.y, vp.y, vn.y)
        ACC16(va.z, vp.z, vn.z)
        ACC16(va.w, vp.w, vn.w)

#pragma unroll
        for (int off = 1; off < 16; off <<= 1) {   // xor stays in 16-lane group
            dp += __shfl_xor(dp, off);
            dn += __shfl_xor(dn, off);
        }
        if (lane15 == 0) {
            const float d_p = sqrtf(fmaxf(dp, 0.f) + EPS_D);
            const float d_n = sqrtf(fmaxf(dn, 0.f) + EPS_D);
            terms[a] = fmaxf(MARGIN_F + d_p - d_n, 0.f);
        }
    }
}

// ---------------- Kernel 4: final reduction (sum of class means) ------------
// 40 blocks (single block was a ~10 us serialized tail). One atomicAdd per
// block (40 same-line atomics ~0.3 us; NOT 2560 like R18 which cost +20 us).
__global__ __launch_bounds__(1024) void reduce_k(
        const float* __restrict__ terms, float* __restrict__ out) {
    __shared__ float red[1024];
    const int tid = threadIdx.x;
    red[tid] = terms[blockIdx.x * 1024 + tid];   // 40*1024 == 40960 exactly
    __syncthreads();
    for (int off = 512; off; off >>= 1) {
        if (tid < off) red[tid] += red[tid + off];
        __syncthreads();
    }
    if (tid == 0) atomicAdd(out, red[0] * (1.0f / (float)P_POS));
}

extern "C" void kernel_launch(void* const* d_in, const int* in_sizes, int n_in,
                              void* d_out, int out_size, void* d_ws, size_t ws_size,
                              hipStream_t stream) {
    const float* feat    = (const float*)d_in[0];
    const int*   pos_idx = (const int*)d_in[1];
    const int*   neg_idx = (const int*)d_in[2];

    char* ws = (char*)d_ws;
    unsigned int* S8 = (unsigned int*)ws;                     // 16 MiB fp8 table
    float*        xx = (float*)(ws + 16777216);               // 256 KiB norms
    unsigned int* hp = (unsigned int*)(ws + 17039360);        // 160 KiB keys
    unsigned int* hn = (unsigned int*)(ws + 17203200);        // 160 KiB keys
    float*     terms = (float*)(ws + 17367040);               // 160 KiB

    sigmoid_norm_k<<<2048, 256, 0, stream>>>(feat, S8, xx, hp, hn,
                                             (float*)d_out);

    select_k<<<32 * 40, 256, 0, stream>>>(S8, xx, pos_idx, neg_idx, hp, hn);

    loss_k<<<640, 256, 0, stream>>>(S8, pos_idx, neg_idx, hp, hn, terms);

    reduce_k<<<40, 1024, 0, stream>>>(terms, (float*)d_out);
}